// Round 5
// baseline (50.096 us; speedup 1.0000x reference)
//
#include <hip/hip_runtime.h>
#include <math.h>

#define KK 27
#define MM 4
#define OUTC 32
#define GG 64
#define GG3 (GG * GG * GG)
#define DILF 0.05f
#define MAXDF 1.0f
#define MU 4e-3f   // ambiguity margin in grid-units (u-space); FP drift bound ~1e-4
#define NBIN1 16   // bins per axis (4-cell-wide bins)
#define NBINS (NBIN1 * NBIN1 * NBIN1)

// Bit-exact (numpy op order, no FMA contraction, IEEE div) in-bounds test.
static __device__ inline bool exact_inb(float lx, float ly, float lz,
                                        float ox, float oy, float oz,
                                        float tx, float ty, float tz,
                                        float qx, float qy, float qz, float qw,
                                        float sc, float gcs) {
#pragma clang fp contract(off)
    float px = lx + ox, py = ly + oy, pz = lz + oz;
    float vx = px - tx, vy = py - ty, vz = pz - tz;
    float ux = -qx, uy = -qy, uz = -qz;
    float cx = uy * vz - uz * vy;
    float cy = uz * vx - ux * vz;
    float cz = ux * vy - uy * vx;
    float twx = cx + qw * vx;
    float twy = cy + qw * vy;
    float twz = cz + qw * vz;
    float rx = vx + 2.0f * (uy * twz - uz * twy);
    float ry = vy + 2.0f * (uz * twx - ux * twz);
    float rz = vz + 2.0f * (ux * twy - uy * twx);
    rx = rx / sc; ry = ry / sc; rz = rz / sc;
    return (rx >= 0.0f) & (rx <= gcs) & (ry >= 0.0f) & (ry <= gcs) &
           (rz >= 0.0f) & (rz <= gcs);
}

static __device__ inline int point_bin(const float* __restrict__ locs,
                                       int b, int n, int N, float sbin) {
    const float* lp = locs + (size_t)(b * N + n) * 3;
    int bx = (int)(lp[0] * sbin); bx = bx < 0 ? 0 : (bx > 15 ? 15 : bx);
    int by = (int)(lp[1] * sbin); by = by < 0 ? 0 : (by > 15 ? 15 : by);
    int bz = (int)(lp[2] * sbin); bz = bz < 0 ? 0 : (bz > 15 ? 15 : bz);
    return b * NBINS + ((bx << 8) | (by << 4) | bz);
}

__global__ __launch_bounds__(256) void zero_kernel(int* __restrict__ hist, int n) {
    int i = blockIdx.x * 256 + threadIdx.x;
    if (i < n) hist[i] = 0;
}

__global__ __launch_bounds__(256) void hist_kernel(
    const float* __restrict__ locs, int* __restrict__ hist,
    int N, int total, float sbin) {
    int i = blockIdx.x * 256 + threadIdx.x;
    if (i >= total) return;
    int b = i / N, n = i - b * N;
    atomicAdd(&hist[point_bin(locs, b, n, N, sbin)], 1);
}

// single-block exclusive scan over nbins (<= 16384) ints, in place
__global__ __launch_bounds__(1024) void scan_kernel(int* __restrict__ hist,
                                                    int nbins) {
    __shared__ int part[1024];
    int t = threadIdx.x;
    int chunk = (nbins + 1023) / 1024;   // <= 16
    int base = t * chunk;
    int v[16];
    int s = 0;
    for (int j = 0; j < chunk; ++j) {
        int idx = base + j;
        v[j] = (idx < nbins) ? hist[idx] : 0;
        s += v[j];
    }
    part[t] = s;
    __syncthreads();
    for (int off = 1; off < 1024; off <<= 1) {
        int x = (t >= off) ? part[t - off] : 0;
        __syncthreads();
        part[t] += x;
        __syncthreads();
    }
    int ex = part[t] - s;   // exclusive prefix of this thread's chunk
    for (int j = 0; j < chunk; ++j) {
        int idx = base + j;
        if (idx < nbins) hist[idx] = ex;
        ex += v[j];
    }
}

__global__ __launch_bounds__(256) void scatter_kernel(
    const float* __restrict__ locs, int* __restrict__ cursor,
    int* __restrict__ perm, int N, int total, float sbin) {
    int i = blockIdx.x * 256 + threadIdx.x;
    if (i >= total) return;
    int b = i / N, n = i - b * N;
    int pos = atomicAdd(&cursor[point_bin(locs, b, n, N, sbin)], 1);
    perm[pos] = n;   // bins are b-major -> pos lies in [b*N, (b+1)*N)
}

// Fused main kernel; lane layout: 4 consecutive lanes = 4 models of one point.
__global__ __launch_bounds__(256) void convsdf_kernel(
    const float* __restrict__ locs, const int* __restrict__ idxs,
    const float* __restrict__ poses, const float* __restrict__ scales,
    const float* __restrict__ sdf, const float* __restrict__ cells,
    const float* __restrict__ weight, const float* __restrict__ bias,
    const int* __restrict__ perm, float* __restrict__ out, int N) {
    __shared__ float4 s_ro[MM][KK];
    __shared__ float4 s_off[KK];
    __shared__ float4 s_wT4[KK * OUTC / 4];
    __shared__ float  s_bias[OUTC];
    __shared__ float  s_t[MM][3];
    __shared__ float  s_q[MM][4];
    __shared__ float  s_sc[MM];
    __shared__ float  s_gcs[MM];
    __shared__ float  s_invscs[MM];
    __shared__ int    s_goff[MM];

    const int b = blockIdx.y;
    const int tid = threadIdx.x;

    float* s_wT = (float*)s_wT4;
    for (int i = tid; i < KK * OUTC; i += 256) {
        int k = i >> 5, o = i & 31;
        s_wT[i] = weight[o * KK + k];
    }
    if (tid < OUTC) s_bias[tid] = bias[tid];
    if (tid < KK) {
        int kx = tid / 9, ky = (tid / 3) % 3, kz = tid % 3;
        s_off[tid] = make_float4((float)(kx - 1) * DILF, (float)(ky - 1) * DILF,
                                 (float)(kz - 1) * DILF, 0.0f);
    }
    if (tid >= 128 && tid < 128 + MM) {
        int m = tid - 128;
        const float* pp = poses + (b * MM + m) * 7;
        float sc = scales[b * MM + m];
        int gi = idxs[b * MM + m];
        float cs = cells[gi];
        s_t[m][0] = pp[0]; s_t[m][1] = pp[1]; s_t[m][2] = pp[2];
        s_q[m][0] = pp[3]; s_q[m][1] = pp[4]; s_q[m][2] = pp[5]; s_q[m][3] = pp[6];
        s_sc[m] = sc;
        s_gcs[m] = (float)GG * cs;
        s_invscs[m] = 1.0f / (sc * cs);
        s_goff[m] = gi * GG3;
    }
    __syncthreads();

    if (tid < MM * KK) {
        int m = tid / KK, k = tid - m * KK;
        float4 off = s_off[k];
        float qx = s_q[m][0], qy = s_q[m][1], qz = s_q[m][2], qw = s_q[m][3];
        float ux = -qx, uy = -qy, uz = -qz;
        float vx = off.x, vy = off.y, vz = off.z;
        float cx = uy * vz - uz * vy + qw * vx;
        float cy = uz * vx - ux * vz + qw * vy;
        float cz = ux * vy - uy * vx + qw * vz;
        float rx = vx + 2.0f * (uy * cz - uz * cy);
        float ry = vy + 2.0f * (uz * cx - ux * cz);
        float rz = vz + 2.0f * (ux * cy - uy * cx);
        float f = s_invscs[m];
        s_ro[m][k] = make_float4(rx * f, ry * f, rz * f, 0.0f);
    }
    __syncthreads();

    const int pl = tid >> 2;          // point-in-block 0..63
    const int m  = tid & 3;           // model 0..3
    const int s_idx = blockIdx.x * 64 + pl;
    if (s_idx >= N) return;
    const int n = perm[b * N + s_idx];   // spatially-sorted point id

    const float* lp = locs + (size_t)(b * N + n) * 3;
    float lx = lp[0], ly = lp[1], lz = lp[2];

    float tx = s_t[m][0], ty = s_t[m][1], tz = s_t[m][2];
    float qx = s_q[m][0], qy = s_q[m][1], qz = s_q[m][2], qw = s_q[m][3];
    float sc = s_sc[m], gcs = s_gcs[m];
    float bux, buy, buz;
    {
        float vx = lx - tx, vy = ly - ty, vz = lz - tz;
        float ux = -qx, uy = -qy, uz = -qz;
        float cx = uy * vz - uz * vy + qw * vx;
        float cy = uz * vx - ux * vz + qw * vy;
        float cz = ux * vy - uy * vx + qw * vz;
        float rx = vx + 2.0f * (uy * cz - uz * cy);
        float ry = vy + 2.0f * (uz * cx - ux * cz);
        float rz = vz + 2.0f * (ux * cy - uy * cx);
        float f = s_invscs[m];
        bux = rx * f; buy = ry * f; buz = rz * f;
    }
    const float* gbase = sdf + s_goff[m];

    float acc[8];
#pragma unroll
    for (int j = 0; j < 8; ++j) acc[j] = s_bias[m * 8 + j];

#pragma unroll 3
    for (int k = 0; k < KK; ++k) {
        float4 ro = s_ro[m][k];
        float ux = bux + ro.x;
        float uy = buy + ro.y;
        float uz = buz + ro.z;
        float mn = fminf(fminf(ux, uy), uz);
        float mx = fmaxf(fmaxf(ux, uy), uz);
        bool inb = (mn >= 0.0f) & (mx <= 64.0f);
        float a0 = fminf(fminf(fabsf(ux), fabsf(uy)), fabsf(uz));
        float a1 = fminf(fminf(fabsf(ux - 64.0f), fabsf(uy - 64.0f)),
                         fabsf(uz - 64.0f));
        if (fminf(a0, a1) < MU) {
            float4 ofk = s_off[k];
            inb = exact_inb(lx, ly, lz, ofk.x, ofk.y, ofk.z,
                            tx, ty, tz, qx, qy, qz, qw, sc, gcs);
        }
        float v = MAXDF;
        if (inb) {   // exec-masked: OOB lanes issue no gather
            float gx = fminf(fmaxf(ux - 0.5f, 0.0f), 63.0f);
            float gy = fminf(fmaxf(uy - 0.5f, 0.0f), 63.0f);
            float gz = fminf(fmaxf(uz - 0.5f, 0.0f), 63.0f);
            int ix = min((int)gx, 62);
            int iy = min((int)gy, 62);
            int iz = min((int)gz, 62);
            float fx = gx - (float)ix;
            float fy = gy - (float)iy;
            float fz = gz - (float)iz;
            const float* g = gbase + ((ix * GG + iy) * GG + iz);
            float v000 = g[0], v001 = g[1];
            float v010 = g[GG], v011 = g[GG + 1];
            float v100 = g[GG * GG], v101 = g[GG * GG + 1];
            float v110 = g[GG * GG + GG], v111 = g[GG * GG + GG + 1];
            float c00 = v000 + fz * (v001 - v000);
            float c01 = v010 + fz * (v011 - v010);
            float c10 = v100 + fz * (v101 - v100);
            float c11 = v110 + fz * (v111 - v110);
            float c0 = c00 + fy * (c01 - c00);
            float c1 = c10 + fy * (c11 - c10);
            v = (c0 + fx * (c1 - c0)) * sc;
        }
        float dk = v;
        dk = fminf(dk, __shfl_xor(dk, 1, 4));
        dk = fminf(dk, __shfl_xor(dk, 2, 4));
        float4 w0 = s_wT4[k * (OUTC / 4) + m * 2 + 0];
        float4 w1 = s_wT4[k * (OUTC / 4) + m * 2 + 1];
        acc[0] += dk * w0.x; acc[1] += dk * w0.y;
        acc[2] += dk * w0.z; acc[3] += dk * w0.w;
        acc[4] += dk * w1.x; acc[5] += dk * w1.y;
        acc[6] += dk * w1.z; acc[7] += dk * w1.w;
    }

    float* op = out + (size_t)(b * N + n) * OUTC + m * 8;
    *(float4*)&op[0] = make_float4(acc[0], acc[1], acc[2], acc[3]);
    *(float4*)&op[4] = make_float4(acc[4], acc[5], acc[6], acc[7]);
}

extern "C" void kernel_launch(void* const* d_in, const int* in_sizes, int n_in,
                              void* d_out, int out_size, void* d_ws, size_t ws_size,
                              hipStream_t stream) {
    const float* locs   = (const float*)d_in[0];
    const int*   idxs   = (const int*)d_in[1];
    const float* poses  = (const float*)d_in[2];
    const float* scales = (const float*)d_in[3];
    const float* sdf    = (const float*)d_in[4];
    const float* cells  = (const float*)d_in[5];
    const float* weight = (const float*)d_in[6];
    const float* bias   = (const float*)d_in[7];
    float* out = (float*)d_out;

    int B = in_sizes[1] / MM;          // idxs is [B, M]
    int N = in_sizes[0] / (3 * B);     // locs is [B, N, 3]
    int total = B * N;
    int nbins = B * NBINS;

    int* hist = (int*)d_ws;            // nbins ints (becomes offsets/cursors)
    int* perm = hist + nbins;          // B*N ints

    // bin scale: 16 bins over extent G*0.031; heuristic only (clamped),
    // correctness does not depend on it.
    float sbin = (float)NBIN1 / ((float)GG * 0.031f);

    zero_kernel<<<(nbins + 255) / 256, 256, 0, stream>>>(hist, nbins);
    hist_kernel<<<(total + 255) / 256, 256, 0, stream>>>(locs, hist, N, total, sbin);
    scan_kernel<<<1, 1024, 0, stream>>>(hist, nbins);
    scatter_kernel<<<(total + 255) / 256, 256, 0, stream>>>(locs, hist, perm,
                                                            N, total, sbin);

    dim3 grid((N + 63) / 64, B);
    convsdf_kernel<<<grid, 256, 0, stream>>>(locs, idxs, poses, scales, sdf,
                                             cells, weight, bias, perm, out, N);
}

// Round 6
// 35.262 us; speedup vs baseline: 1.4207x; 1.4207x over previous
//
#include <hip/hip_runtime.h>
#include <hip/hip_fp16.h>
#include <math.h>

#define KK 27
#define MM 4
#define OUTC 32
#define GG 64
#define GG3 (GG * GG * GG)
#define DILF 0.05f
#define MAXDF 1.0f
#define MU 4e-3f   // ambiguity margin in grid-units (u-space); FP drift bound ~1e-4

// Bit-exact (numpy op order, no FMA contraction, IEEE div) in-bounds test.
static __device__ inline bool exact_inb(float lx, float ly, float lz,
                                        float ox, float oy, float oz,
                                        float tx, float ty, float tz,
                                        float qx, float qy, float qz, float qw,
                                        float sc, float gcs) {
#pragma clang fp contract(off)
    float px = lx + ox, py = ly + oy, pz = lz + oz;
    float vx = px - tx, vy = py - ty, vz = pz - tz;
    float ux = -qx, uy = -qy, uz = -qz;
    float cx = uy * vz - uz * vy;
    float cy = uz * vx - ux * vz;
    float cz = ux * vy - uy * vx;
    float twx = cx + qw * vx;
    float twy = cy + qw * vy;
    float twz = cz + qw * vz;
    float rx = vx + 2.0f * (uy * twz - uz * twy);
    float ry = vy + 2.0f * (uz * twx - ux * twz);
    float rz = vz + 2.0f * (ux * twy - uy * twx);
    rx = rx / sc; ry = ry / sc; rz = rz / sc;
    return (rx >= 0.0f) & (rx <= gcs) & (ry >= 0.0f) & (ry <= gcs) &
           (rz >= 0.0f) & (rz <= gcs);
}

// ---- Repack: quad[j][x][y][z] = {v(x,y,z),v(x,y,z+1),v(x+1,y,z),v(x+1,y,z+1)}
//      packed as 2x __half2 in a uint2 (8 B per cell).
__global__ __launch_bounds__(256) void repack_kernel(
    const float* __restrict__ sdf, const int* __restrict__ idxs,
    uint2* __restrict__ quad, int nslots) {
    const int j = blockIdx.y;
    __shared__ int ref;
    if (threadIdx.x == 0) {
        int r = 0;
        for (int s = 0; s < nslots; ++s) r |= (idxs[s] == j) ? 1 : 0;
        ref = r;
    }
    __syncthreads();
    if (!ref) return;

    int i = blockIdx.x * 256 + threadIdx.x;   // 0..GG3-1
    int x = i >> 12, y = (i >> 6) & 63, z = i & 63;
    int xp = min(x + 1, 63), zp = min(z + 1, 63);
    const float* g = sdf + (size_t)j * GG3;
    float v000 = g[(x * GG + y) * GG + z];
    float v001 = g[(x * GG + y) * GG + zp];
    float v100 = g[(xp * GG + y) * GG + z];
    float v101 = g[(xp * GG + y) * GG + zp];
    __half2 h0 = __floats2half2_rn(v000, v001);
    __half2 h1 = __floats2half2_rn(v100, v101);
    uint2 o;
    o.x = *(unsigned int*)&h0;
    o.y = *(unsigned int*)&h1;
    quad[(size_t)j * GG3 + i] = o;
}

// Fused main kernel; lane layout: 4 consecutive lanes = 4 models of one point.
// Trilinear sample = TWO 8B gathers (rows y and y+1) from the quad grid.
__global__ __launch_bounds__(256) void convsdf_quad_kernel(
    const float* __restrict__ locs, const int* __restrict__ idxs,
    const float* __restrict__ poses, const float* __restrict__ scales,
    const uint2* __restrict__ quad, const float* __restrict__ cells,
    const float* __restrict__ weight, const float* __restrict__ bias,
    float* __restrict__ out, int N) {
    __shared__ float4 s_ro[MM][KK];
    __shared__ float4 s_off[KK];
    __shared__ float4 s_wT4[KK * OUTC / 4];
    __shared__ float  s_bias[OUTC];
    __shared__ float  s_t[MM][3];
    __shared__ float  s_q[MM][4];
    __shared__ float  s_sc[MM];
    __shared__ float  s_gcs[MM];
    __shared__ float  s_invscs[MM];
    __shared__ int    s_goff[MM];

    const int b = blockIdx.y;
    const int tid = threadIdx.x;

    float* s_wT = (float*)s_wT4;
    for (int i = tid; i < KK * OUTC; i += 256) {
        int k = i >> 5, o = i & 31;
        s_wT[i] = weight[o * KK + k];
    }
    if (tid < OUTC) s_bias[tid] = bias[tid];
    if (tid < KK) {
        int kx = tid / 9, ky = (tid / 3) % 3, kz = tid % 3;
        s_off[tid] = make_float4((float)(kx - 1) * DILF, (float)(ky - 1) * DILF,
                                 (float)(kz - 1) * DILF, 0.0f);
    }
    if (tid >= 128 && tid < 128 + MM) {
        int m = tid - 128;
        const float* pp = poses + (b * MM + m) * 7;
        float sc = scales[b * MM + m];
        int gi = idxs[b * MM + m];
        float cs = cells[gi];
        s_t[m][0] = pp[0]; s_t[m][1] = pp[1]; s_t[m][2] = pp[2];
        s_q[m][0] = pp[3]; s_q[m][1] = pp[4]; s_q[m][2] = pp[5]; s_q[m][3] = pp[6];
        s_sc[m] = sc;
        s_gcs[m] = (float)GG * cs;
        s_invscs[m] = 1.0f / (sc * cs);
        s_goff[m] = gi * GG3;
    }
    __syncthreads();

    if (tid < MM * KK) {
        int m = tid / KK, k = tid - m * KK;
        float4 off = s_off[k];
        float qx = s_q[m][0], qy = s_q[m][1], qz = s_q[m][2], qw = s_q[m][3];
        float ux = -qx, uy = -qy, uz = -qz;
        float vx = off.x, vy = off.y, vz = off.z;
        float cx = uy * vz - uz * vy + qw * vx;
        float cy = uz * vx - ux * vz + qw * vy;
        float cz = ux * vy - uy * vx + qw * vz;
        float rx = vx + 2.0f * (uy * cz - uz * cy);
        float ry = vy + 2.0f * (uz * cx - ux * cz);
        float rz = vz + 2.0f * (ux * cy - uy * cx);
        float f = s_invscs[m];
        s_ro[m][k] = make_float4(rx * f, ry * f, rz * f, 0.0f);
    }
    __syncthreads();

    const int pl = tid >> 2;          // point-in-block 0..63
    const int m  = tid & 3;           // model 0..3
    const int n  = blockIdx.x * 64 + pl;
    if (n >= N) return;

    const float* lp = locs + (size_t)(b * N + n) * 3;
    float lx = lp[0], ly = lp[1], lz = lp[2];

    float tx = s_t[m][0], ty = s_t[m][1], tz = s_t[m][2];
    float qx = s_q[m][0], qy = s_q[m][1], qz = s_q[m][2], qw = s_q[m][3];
    float sc = s_sc[m], gcs = s_gcs[m];
    float bux, buy, buz;
    {
        float vx = lx - tx, vy = ly - ty, vz = lz - tz;
        float ux = -qx, uy = -qy, uz = -qz;
        float cx = uy * vz - uz * vy + qw * vx;
        float cy = uz * vx - ux * vz + qw * vy;
        float cz = ux * vy - uy * vx + qw * vz;
        float rx = vx + 2.0f * (uy * cz - uz * cy);
        float ry = vy + 2.0f * (uz * cx - ux * cz);
        float rz = vz + 2.0f * (ux * cy - uy * cx);
        float f = s_invscs[m];
        bux = rx * f; buy = ry * f; buz = rz * f;
    }
    const uint2* qg = quad + s_goff[m];

    float acc[8];
#pragma unroll
    for (int j = 0; j < 8; ++j) acc[j] = s_bias[m * 8 + j];

#pragma unroll 3
    for (int k = 0; k < KK; ++k) {
        float4 ro = s_ro[m][k];
        float ux = bux + ro.x;
        float uy = buy + ro.y;
        float uz = buz + ro.z;
        float mn = fminf(fminf(ux, uy), uz);
        float mx = fmaxf(fmaxf(ux, uy), uz);
        bool inb = (mn >= 0.0f) & (mx <= 64.0f);
        float a0 = fminf(fminf(fabsf(ux), fabsf(uy)), fabsf(uz));
        float a1 = fminf(fminf(fabsf(ux - 64.0f), fabsf(uy - 64.0f)),
                         fabsf(uz - 64.0f));
        if (fminf(a0, a1) < MU) {
            float4 ofk = s_off[k];
            inb = exact_inb(lx, ly, lz, ofk.x, ofk.y, ofk.z,
                            tx, ty, tz, qx, qy, qz, qw, sc, gcs);
        }
        float v = MAXDF;
        if (inb) {   // exec-masked: OOB lanes issue no gathers
            float gx = fminf(fmaxf(ux - 0.5f, 0.0f), 63.0f);
            float gy = fminf(fmaxf(uy - 0.5f, 0.0f), 63.0f);
            float gz = fminf(fmaxf(uz - 0.5f, 0.0f), 63.0f);
            int ix = min((int)gx, 62);
            int iy = min((int)gy, 62);
            int iz = min((int)gz, 62);
            float fx = gx - (float)ix;
            float fy = gy - (float)iy;
            float fz = gz - (float)iz;
            int base = (ix * GG + iy) * GG + iz;
            uint2 qa = qg[base];        // row (x, y):   v000,v001 | v100,v101
            uint2 qb = qg[base + GG];   // row (x, y+1): v010,v011 | v110,v111
            float2 az  = __half22float2(*(__half2*)&qa.x);
            float2 axz = __half22float2(*(__half2*)&qa.y);
            float2 bz  = __half22float2(*(__half2*)&qb.x);
            float2 bxz = __half22float2(*(__half2*)&qb.y);
            float c00 = az.x  + fz * (az.y  - az.x);   // (x,   y)
            float c10 = axz.x + fz * (axz.y - axz.x);  // (x+1, y)
            float c01 = bz.x  + fz * (bz.y  - bz.x);   // (x,   y+1)
            float c11 = bxz.x + fz * (bxz.y - bxz.x);  // (x+1, y+1)
            float c0 = c00 + fy * (c01 - c00);
            float c1 = c10 + fy * (c11 - c10);
            v = (c0 + fx * (c1 - c0)) * sc;
        }
        float dk = v;
        dk = fminf(dk, __shfl_xor(dk, 1, 4));
        dk = fminf(dk, __shfl_xor(dk, 2, 4));
        float4 w0 = s_wT4[k * (OUTC / 4) + m * 2 + 0];
        float4 w1 = s_wT4[k * (OUTC / 4) + m * 2 + 1];
        acc[0] += dk * w0.x; acc[1] += dk * w0.y;
        acc[2] += dk * w0.z; acc[3] += dk * w0.w;
        acc[4] += dk * w1.x; acc[5] += dk * w1.y;
        acc[6] += dk * w1.z; acc[7] += dk * w1.w;
    }

    float* op = out + (size_t)(b * N + n) * OUTC + m * 8;
    *(float4*)&op[0] = make_float4(acc[0], acc[1], acc[2], acc[3]);
    *(float4*)&op[4] = make_float4(acc[4], acc[5], acc[6], acc[7]);
}

// ---------------- Fallback: direct f32 8-gather fused kernel (R3) -----------
__global__ __launch_bounds__(256) void convsdf_direct_kernel(
    const float* __restrict__ locs, const int* __restrict__ idxs,
    const float* __restrict__ poses, const float* __restrict__ scales,
    const float* __restrict__ sdf, const float* __restrict__ cells,
    const float* __restrict__ weight, const float* __restrict__ bias,
    float* __restrict__ out, int N) {
    __shared__ float4 s_ro[MM][KK];
    __shared__ float4 s_off[KK];
    __shared__ float4 s_wT4[KK * OUTC / 4];
    __shared__ float  s_bias[OUTC];
    __shared__ float  s_t[MM][3];
    __shared__ float  s_q[MM][4];
    __shared__ float  s_sc[MM];
    __shared__ float  s_gcs[MM];
    __shared__ float  s_invscs[MM];
    __shared__ int    s_goff[MM];

    const int b = blockIdx.y;
    const int tid = threadIdx.x;

    float* s_wT = (float*)s_wT4;
    for (int i = tid; i < KK * OUTC; i += 256) {
        int k = i >> 5, o = i & 31;
        s_wT[i] = weight[o * KK + k];
    }
    if (tid < OUTC) s_bias[tid] = bias[tid];
    if (tid < KK) {
        int kx = tid / 9, ky = (tid / 3) % 3, kz = tid % 3;
        s_off[tid] = make_float4((float)(kx - 1) * DILF, (float)(ky - 1) * DILF,
                                 (float)(kz - 1) * DILF, 0.0f);
    }
    if (tid >= 128 && tid < 128 + MM) {
        int m = tid - 128;
        const float* pp = poses + (b * MM + m) * 7;
        float sc = scales[b * MM + m];
        int gi = idxs[b * MM + m];
        float cs = cells[gi];
        s_t[m][0] = pp[0]; s_t[m][1] = pp[1]; s_t[m][2] = pp[2];
        s_q[m][0] = pp[3]; s_q[m][1] = pp[4]; s_q[m][2] = pp[5]; s_q[m][3] = pp[6];
        s_sc[m] = sc;
        s_gcs[m] = (float)GG * cs;
        s_invscs[m] = 1.0f / (sc * cs);
        s_goff[m] = gi * GG3;
    }
    __syncthreads();

    if (tid < MM * KK) {
        int m = tid / KK, k = tid - m * KK;
        float4 off = s_off[k];
        float qx = s_q[m][0], qy = s_q[m][1], qz = s_q[m][2], qw = s_q[m][3];
        float ux = -qx, uy = -qy, uz = -qz;
        float vx = off.x, vy = off.y, vz = off.z;
        float cx = uy * vz - uz * vy + qw * vx;
        float cy = uz * vx - ux * vz + qw * vy;
        float cz = ux * vy - uy * vx + qw * vz;
        float rx = vx + 2.0f * (uy * cz - uz * cy);
        float ry = vy + 2.0f * (uz * cx - ux * cz);
        float rz = vz + 2.0f * (ux * cy - uy * cx);
        float f = s_invscs[m];
        s_ro[m][k] = make_float4(rx * f, ry * f, rz * f, 0.0f);
    }
    __syncthreads();

    const int pl = tid >> 2;
    const int m  = tid & 3;
    const int n  = blockIdx.x * 64 + pl;
    if (n >= N) return;

    const float* lp = locs + (size_t)(b * N + n) * 3;
    float lx = lp[0], ly = lp[1], lz = lp[2];

    float tx = s_t[m][0], ty = s_t[m][1], tz = s_t[m][2];
    float qx = s_q[m][0], qy = s_q[m][1], qz = s_q[m][2], qw = s_q[m][3];
    float sc = s_sc[m], gcs = s_gcs[m];
    float bux, buy, buz;
    {
        float vx = lx - tx, vy = ly - ty, vz = lz - tz;
        float ux = -qx, uy = -qy, uz = -qz;
        float cx = uy * vz - uz * vy + qw * vx;
        float cy = uz * vx - ux * vz + qw * vy;
        float cz = ux * vy - uy * vx + qw * vz;
        float rx = vx + 2.0f * (uy * cz - uz * cy);
        float ry = vy + 2.0f * (uz * cx - ux * cz);
        float rz = vz + 2.0f * (ux * cy - uy * cx);
        float f = s_invscs[m];
        bux = rx * f; buy = ry * f; buz = rz * f;
    }
    const float* gbase = sdf + s_goff[m];

    float acc[8];
#pragma unroll
    for (int j = 0; j < 8; ++j) acc[j] = s_bias[m * 8 + j];

#pragma unroll 3
    for (int k = 0; k < KK; ++k) {
        float4 ro = s_ro[m][k];
        float ux = bux + ro.x;
        float uy = buy + ro.y;
        float uz = buz + ro.z;
        float mn = fminf(fminf(ux, uy), uz);
        float mx = fmaxf(fmaxf(ux, uy), uz);
        bool inb = (mn >= 0.0f) & (mx <= 64.0f);
        float a0 = fminf(fminf(fabsf(ux), fabsf(uy)), fabsf(uz));
        float a1 = fminf(fminf(fabsf(ux - 64.0f), fabsf(uy - 64.0f)),
                         fabsf(uz - 64.0f));
        if (fminf(a0, a1) < MU) {
            float4 ofk = s_off[k];
            inb = exact_inb(lx, ly, lz, ofk.x, ofk.y, ofk.z,
                            tx, ty, tz, qx, qy, qz, qw, sc, gcs);
        }
        float v = MAXDF;
        if (inb) {
            float gx = fminf(fmaxf(ux - 0.5f, 0.0f), 63.0f);
            float gy = fminf(fmaxf(uy - 0.5f, 0.0f), 63.0f);
            float gz = fminf(fmaxf(uz - 0.5f, 0.0f), 63.0f);
            int ix = min((int)gx, 62);
            int iy = min((int)gy, 62);
            int iz = min((int)gz, 62);
            float fx = gx - (float)ix;
            float fy = gy - (float)iy;
            float fz = gz - (float)iz;
            const float* g = gbase + ((ix * GG + iy) * GG + iz);
            float v000 = g[0], v001 = g[1];
            float v010 = g[GG], v011 = g[GG + 1];
            float v100 = g[GG * GG], v101 = g[GG * GG + 1];
            float v110 = g[GG * GG + GG], v111 = g[GG * GG + GG + 1];
            float c00 = v000 + fz * (v001 - v000);
            float c01 = v010 + fz * (v011 - v010);
            float c10 = v100 + fz * (v101 - v100);
            float c11 = v110 + fz * (v111 - v110);
            float c0 = c00 + fy * (c01 - c00);
            float c1 = c10 + fy * (c11 - c10);
            v = (c0 + fx * (c1 - c0)) * sc;
        }
        float dk = v;
        dk = fminf(dk, __shfl_xor(dk, 1, 4));
        dk = fminf(dk, __shfl_xor(dk, 2, 4));
        float4 w0 = s_wT4[k * (OUTC / 4) + m * 2 + 0];
        float4 w1 = s_wT4[k * (OUTC / 4) + m * 2 + 1];
        acc[0] += dk * w0.x; acc[1] += dk * w0.y;
        acc[2] += dk * w0.z; acc[3] += dk * w0.w;
        acc[4] += dk * w1.x; acc[5] += dk * w1.y;
        acc[6] += dk * w1.z; acc[7] += dk * w1.w;
    }

    float* op = out + (size_t)(b * N + n) * OUTC + m * 8;
    *(float4*)&op[0] = make_float4(acc[0], acc[1], acc[2], acc[3]);
    *(float4*)&op[4] = make_float4(acc[4], acc[5], acc[6], acc[7]);
}

extern "C" void kernel_launch(void* const* d_in, const int* in_sizes, int n_in,
                              void* d_out, int out_size, void* d_ws, size_t ws_size,
                              hipStream_t stream) {
    const float* locs   = (const float*)d_in[0];
    const int*   idxs   = (const int*)d_in[1];
    const float* poses  = (const float*)d_in[2];
    const float* scales = (const float*)d_in[3];
    const float* sdf    = (const float*)d_in[4];
    const float* cells  = (const float*)d_in[5];
    const float* weight = (const float*)d_in[6];
    const float* bias   = (const float*)d_in[7];
    float* out = (float*)d_out;

    int B = in_sizes[1] / MM;          // idxs is [B, M]
    int N = in_sizes[0] / (3 * B);     // locs is [B, N, 3]
    int NSDF = in_sizes[4] / GG3;      // sdf_grid is [NSDF, G, G, G]
    int nslots = in_sizes[1];          // B*M

    size_t quad_bytes = (size_t)NSDF * GG3 * 8;
    dim3 grid((N + 63) / 64, B);

    if (ws_size >= quad_bytes) {
        uint2* quad = (uint2*)d_ws;
        dim3 gridR(GG3 / 256, NSDF);
        repack_kernel<<<gridR, 256, 0, stream>>>(sdf, idxs, quad, nslots);
        convsdf_quad_kernel<<<grid, 256, 0, stream>>>(locs, idxs, poses, scales,
                                                      quad, cells, weight, bias,
                                                      out, N);
    } else {
        convsdf_direct_kernel<<<grid, 256, 0, stream>>>(locs, idxs, poses,
                                                        scales, sdf, cells,
                                                        weight, bias, out, N);
    }
}

// Round 7
// 34.545 us; speedup vs baseline: 1.4502x; 1.0208x over previous
//
#include <hip/hip_runtime.h>
#include <hip/hip_fp16.h>
#include <math.h>

#define KK 27
#define MM 4
#define OUTC 32
#define GG 64
#define GG3 (GG * GG * GG)
#define DILF 0.05f
#define MAXDF 1.0f
#define MU 4e-3f   // ambiguity margin in grid-units (u-space); FP drift bound ~1e-4

// Bit-exact (numpy op order, no FMA contraction, IEEE div) in-bounds test.
static __device__ inline bool exact_inb(float lx, float ly, float lz,
                                        float ox, float oy, float oz,
                                        float tx, float ty, float tz,
                                        float qx, float qy, float qz, float qw,
                                        float sc, float gcs) {
#pragma clang fp contract(off)
    float px = lx + ox, py = ly + oy, pz = lz + oz;
    float vx = px - tx, vy = py - ty, vz = pz - tz;
    float ux = -qx, uy = -qy, uz = -qz;
    float cx = uy * vz - uz * vy;
    float cy = uz * vx - ux * vz;
    float cz = ux * vy - uy * vx;
    float twx = cx + qw * vx;
    float twy = cy + qw * vy;
    float twz = cz + qw * vz;
    float rx = vx + 2.0f * (uy * twz - uz * twy);
    float ry = vy + 2.0f * (uz * twx - ux * twz);
    float rz = vz + 2.0f * (ux * twy - uy * twx);
    rx = rx / sc; ry = ry / sc; rz = rz / sc;
    return (rx >= 0.0f) & (rx <= gcs) & (ry >= 0.0f) & (ry <= gcs) &
           (rz >= 0.0f) & (rz <= gcs);
}

// ---- Repack: zp[j][x][y][z] = {v(x,y,z), v(x,y,z+1)} as __half2 (4 B/cell).
//      Footprint = 1 MB/grid, SAME as f32 -> stays per-XCD-L2-resident.
__global__ __launch_bounds__(256) void repack_kernel(
    const float* __restrict__ sdf, const int* __restrict__ idxs,
    unsigned int* __restrict__ zp, int nslots) {
    const int j = blockIdx.y;
    __shared__ int ref;
    if (threadIdx.x == 0) {
        int r = 0;
        for (int s = 0; s < nslots; ++s) r |= (idxs[s] == j) ? 1 : 0;
        ref = r;
    }
    __syncthreads();
    if (!ref) return;

    int i = blockIdx.x * 256 + threadIdx.x;   // 0..GG3-1, z fastest
    int z = i & 63;
    const float* g = sdf + (size_t)j * GG3;
    float v0 = g[i];
    float v1 = g[z == 63 ? i : i + 1];
    __half2 h = __floats2half2_rn(v0, v1);
    zp[(size_t)j * GG3 + i] = *(unsigned int*)&h;
}

// Fused main kernel; lane layout: 4 consecutive lanes = 4 models of one point.
// Trilinear sample = FOUR 4B row-gathers from the z-pair grid.
__global__ __launch_bounds__(256) void convsdf_zp_kernel(
    const float* __restrict__ locs, const int* __restrict__ idxs,
    const float* __restrict__ poses, const float* __restrict__ scales,
    const unsigned int* __restrict__ zp, const float* __restrict__ cells,
    const float* __restrict__ weight, const float* __restrict__ bias,
    float* __restrict__ out, int N) {
    __shared__ float4 s_ro[MM][KK];
    __shared__ float4 s_off[KK];
    __shared__ float4 s_wT4[KK * OUTC / 4];
    __shared__ float  s_bias[OUTC];
    __shared__ float  s_t[MM][3];
    __shared__ float  s_q[MM][4];
    __shared__ float  s_sc[MM];
    __shared__ float  s_gcs[MM];
    __shared__ float  s_invscs[MM];
    __shared__ int    s_goff[MM];

    const int b = blockIdx.y;
    const int tid = threadIdx.x;

    float* s_wT = (float*)s_wT4;
    for (int i = tid; i < KK * OUTC; i += 256) {
        int k = i >> 5, o = i & 31;
        s_wT[i] = weight[o * KK + k];
    }
    if (tid < OUTC) s_bias[tid] = bias[tid];
    if (tid < KK) {
        int kx = tid / 9, ky = (tid / 3) % 3, kz = tid % 3;
        s_off[tid] = make_float4((float)(kx - 1) * DILF, (float)(ky - 1) * DILF,
                                 (float)(kz - 1) * DILF, 0.0f);
    }
    if (tid >= 128 && tid < 128 + MM) {
        int m = tid - 128;
        const float* pp = poses + (b * MM + m) * 7;
        float sc = scales[b * MM + m];
        int gi = idxs[b * MM + m];
        float cs = cells[gi];
        s_t[m][0] = pp[0]; s_t[m][1] = pp[1]; s_t[m][2] = pp[2];
        s_q[m][0] = pp[3]; s_q[m][1] = pp[4]; s_q[m][2] = pp[5]; s_q[m][3] = pp[6];
        s_sc[m] = sc;
        s_gcs[m] = (float)GG * cs;
        s_invscs[m] = 1.0f / (sc * cs);
        s_goff[m] = gi * GG3;
    }
    __syncthreads();

    if (tid < MM * KK) {
        int m = tid / KK, k = tid - m * KK;
        float4 off = s_off[k];
        float qx = s_q[m][0], qy = s_q[m][1], qz = s_q[m][2], qw = s_q[m][3];
        float ux = -qx, uy = -qy, uz = -qz;
        float vx = off.x, vy = off.y, vz = off.z;
        float cx = uy * vz - uz * vy + qw * vx;
        float cy = uz * vx - ux * vz + qw * vy;
        float cz = ux * vy - uy * vx + qw * vz;
        float rx = vx + 2.0f * (uy * cz - uz * cy);
        float ry = vy + 2.0f * (uz * cx - ux * cz);
        float rz = vz + 2.0f * (ux * cy - uy * cx);
        float f = s_invscs[m];
        s_ro[m][k] = make_float4(rx * f, ry * f, rz * f, 0.0f);
    }
    __syncthreads();

    const int pl = tid >> 2;          // point-in-block 0..63
    const int m  = tid & 3;           // model 0..3
    const int n  = blockIdx.x * 64 + pl;
    if (n >= N) return;

    const float* lp = locs + (size_t)(b * N + n) * 3;
    float lx = lp[0], ly = lp[1], lz = lp[2];

    float tx = s_t[m][0], ty = s_t[m][1], tz = s_t[m][2];
    float qx = s_q[m][0], qy = s_q[m][1], qz = s_q[m][2], qw = s_q[m][3];
    float sc = s_sc[m], gcs = s_gcs[m];
    float bux, buy, buz;
    {
        float vx = lx - tx, vy = ly - ty, vz = lz - tz;
        float ux = -qx, uy = -qy, uz = -qz;
        float cx = uy * vz - uz * vy + qw * vx;
        float cy = uz * vx - ux * vz + qw * vy;
        float cz = ux * vy - uy * vx + qw * vz;
        float rx = vx + 2.0f * (uy * cz - uz * cy);
        float ry = vy + 2.0f * (uz * cx - ux * cz);
        float rz = vz + 2.0f * (ux * cy - uy * cx);
        float f = s_invscs[m];
        bux = rx * f; buy = ry * f; buz = rz * f;
    }
    const unsigned int* zg = zp + s_goff[m];

    float acc[8];
#pragma unroll
    for (int j = 0; j < 8; ++j) acc[j] = s_bias[m * 8 + j];

#pragma unroll 3
    for (int k = 0; k < KK; ++k) {
        float4 ro = s_ro[m][k];
        float ux = bux + ro.x;
        float uy = buy + ro.y;
        float uz = buz + ro.z;
        float mn = fminf(fminf(ux, uy), uz);
        float mx = fmaxf(fmaxf(ux, uy), uz);
        bool inb = (mn >= 0.0f) & (mx <= 64.0f);
        // ambiguity from mn/mx alone: matters only if no axis is definitively
        // outside; then "axis within MU of 0" <=> mn<MU, "within MU of 64"
        // <=> mx>64-MU.
        if ((mn > -MU) & (mx < 64.0f + MU) &
            ((mn < MU) | (mx > 64.0f - MU))) {
            float4 ofk = s_off[k];
            inb = exact_inb(lx, ly, lz, ofk.x, ofk.y, ofk.z,
                            tx, ty, tz, qx, qy, qz, qw, sc, gcs);
        }
        float v = MAXDF;
        if (inb) {   // exec-masked: OOB lanes issue no gathers
            float gx = fminf(fmaxf(ux - 0.5f, 0.0f), 63.0f);
            float gy = fminf(fmaxf(uy - 0.5f, 0.0f), 63.0f);
            float gz = fminf(fmaxf(uz - 0.5f, 0.0f), 63.0f);
            int ix = min((int)gx, 62);
            int iy = min((int)gy, 62);
            int iz = min((int)gz, 62);
            float fx = gx - (float)ix;
            float fy = gy - (float)iy;
            float fz = gz - (float)iz;
            int base = (ix * GG + iy) * GG + iz;
            unsigned int r00 = zg[base];                 // (x,   y)
            unsigned int r01 = zg[base + GG];            // (x,   y+1)
            unsigned int r10 = zg[base + GG * GG];       // (x+1, y)
            unsigned int r11 = zg[base + GG * GG + GG];  // (x+1, y+1)
            float2 p00 = __half22float2(*(__half2*)&r00);
            float2 p01 = __half22float2(*(__half2*)&r01);
            float2 p10 = __half22float2(*(__half2*)&r10);
            float2 p11 = __half22float2(*(__half2*)&r11);
            float c00 = p00.x + fz * (p00.y - p00.x);
            float c01 = p01.x + fz * (p01.y - p01.x);
            float c10 = p10.x + fz * (p10.y - p10.x);
            float c11 = p11.x + fz * (p11.y - p11.x);
            float c0 = c00 + fy * (c01 - c00);
            float c1 = c10 + fy * (c11 - c10);
            v = (c0 + fx * (c1 - c0)) * sc;
        }
        float dk = v;
        dk = fminf(dk, __shfl_xor(dk, 1, 4));
        dk = fminf(dk, __shfl_xor(dk, 2, 4));
        float4 w0 = s_wT4[k * (OUTC / 4) + m * 2 + 0];
        float4 w1 = s_wT4[k * (OUTC / 4) + m * 2 + 1];
        acc[0] += dk * w0.x; acc[1] += dk * w0.y;
        acc[2] += dk * w0.z; acc[3] += dk * w0.w;
        acc[4] += dk * w1.x; acc[5] += dk * w1.y;
        acc[6] += dk * w1.z; acc[7] += dk * w1.w;
    }

    float* op = out + (size_t)(b * N + n) * OUTC + m * 8;
    *(float4*)&op[0] = make_float4(acc[0], acc[1], acc[2], acc[3]);
    *(float4*)&op[4] = make_float4(acc[4], acc[5], acc[6], acc[7]);
}

// ---------------- Fallback: direct f32 8-gather fused kernel (R3) -----------
__global__ __launch_bounds__(256) void convsdf_direct_kernel(
    const float* __restrict__ locs, const int* __restrict__ idxs,
    const float* __restrict__ poses, const float* __restrict__ scales,
    const float* __restrict__ sdf, const float* __restrict__ cells,
    const float* __restrict__ weight, const float* __restrict__ bias,
    float* __restrict__ out, int N) {
    __shared__ float4 s_ro[MM][KK];
    __shared__ float4 s_off[KK];
    __shared__ float4 s_wT4[KK * OUTC / 4];
    __shared__ float  s_bias[OUTC];
    __shared__ float  s_t[MM][3];
    __shared__ float  s_q[MM][4];
    __shared__ float  s_sc[MM];
    __shared__ float  s_gcs[MM];
    __shared__ float  s_invscs[MM];
    __shared__ int    s_goff[MM];

    const int b = blockIdx.y;
    const int tid = threadIdx.x;

    float* s_wT = (float*)s_wT4;
    for (int i = tid; i < KK * OUTC; i += 256) {
        int k = i >> 5, o = i & 31;
        s_wT[i] = weight[o * KK + k];
    }
    if (tid < OUTC) s_bias[tid] = bias[tid];
    if (tid < KK) {
        int kx = tid / 9, ky = (tid / 3) % 3, kz = tid % 3;
        s_off[tid] = make_float4((float)(kx - 1) * DILF, (float)(ky - 1) * DILF,
                                 (float)(kz - 1) * DILF, 0.0f);
    }
    if (tid >= 128 && tid < 128 + MM) {
        int m = tid - 128;
        const float* pp = poses + (b * MM + m) * 7;
        float sc = scales[b * MM + m];
        int gi = idxs[b * MM + m];
        float cs = cells[gi];
        s_t[m][0] = pp[0]; s_t[m][1] = pp[1]; s_t[m][2] = pp[2];
        s_q[m][0] = pp[3]; s_q[m][1] = pp[4]; s_q[m][2] = pp[5]; s_q[m][3] = pp[6];
        s_sc[m] = sc;
        s_gcs[m] = (float)GG * cs;
        s_invscs[m] = 1.0f / (sc * cs);
        s_goff[m] = gi * GG3;
    }
    __syncthreads();

    if (tid < MM * KK) {
        int m = tid / KK, k = tid - m * KK;
        float4 off = s_off[k];
        float qx = s_q[m][0], qy = s_q[m][1], qz = s_q[m][2], qw = s_q[m][3];
        float ux = -qx, uy = -qy, uz = -qz;
        float vx = off.x, vy = off.y, vz = off.z;
        float cx = uy * vz - uz * vy + qw * vx;
        float cy = uz * vx - ux * vz + qw * vy;
        float cz = ux * vy - uy * vx + qw * vz;
        float rx = vx + 2.0f * (uy * cz - uz * cy);
        float ry = vy + 2.0f * (uz * cx - ux * cz);
        float rz = vz + 2.0f * (ux * cy - uy * cx);
        float f = s_invscs[m];
        s_ro[m][k] = make_float4(rx * f, ry * f, rz * f, 0.0f);
    }
    __syncthreads();

    const int pl = tid >> 2;
    const int m  = tid & 3;
    const int n  = blockIdx.x * 64 + pl;
    if (n >= N) return;

    const float* lp = locs + (size_t)(b * N + n) * 3;
    float lx = lp[0], ly = lp[1], lz = lp[2];

    float tx = s_t[m][0], ty = s_t[m][1], tz = s_t[m][2];
    float qx = s_q[m][0], qy = s_q[m][1], qz = s_q[m][2], qw = s_q[m][3];
    float sc = s_sc[m], gcs = s_gcs[m];
    float bux, buy, buz;
    {
        float vx = lx - tx, vy = ly - ty, vz = lz - tz;
        float ux = -qx, uy = -qy, uz = -qz;
        float cx = uy * vz - uz * vy + qw * vx;
        float cy = uz * vx - ux * vz + qw * vy;
        float cz = ux * vy - uy * vx + qw * vz;
        float rx = vx + 2.0f * (uy * cz - uz * cy);
        float ry = vy + 2.0f * (uz * cx - ux * cz);
        float rz = vz + 2.0f * (ux * cy - uy * cx);
        float f = s_invscs[m];
        bux = rx * f; buy = ry * f; buz = rz * f;
    }
    const float* gbase = sdf + s_goff[m];

    float acc[8];
#pragma unroll
    for (int j = 0; j < 8; ++j) acc[j] = s_bias[m * 8 + j];

#pragma unroll 3
    for (int k = 0; k < KK; ++k) {
        float4 ro = s_ro[m][k];
        float ux = bux + ro.x;
        float uy = buy + ro.y;
        float uz = buz + ro.z;
        float mn = fminf(fminf(ux, uy), uz);
        float mx = fmaxf(fmaxf(ux, uy), uz);
        bool inb = (mn >= 0.0f) & (mx <= 64.0f);
        if ((mn > -MU) & (mx < 64.0f + MU) &
            ((mn < MU) | (mx > 64.0f - MU))) {
            float4 ofk = s_off[k];
            inb = exact_inb(lx, ly, lz, ofk.x, ofk.y, ofk.z,
                            tx, ty, tz, qx, qy, qz, qw, sc, gcs);
        }
        float v = MAXDF;
        if (inb) {
            float gx = fminf(fmaxf(ux - 0.5f, 0.0f), 63.0f);
            float gy = fminf(fmaxf(uy - 0.5f, 0.0f), 63.0f);
            float gz = fminf(fmaxf(uz - 0.5f, 0.0f), 63.0f);
            int ix = min((int)gx, 62);
            int iy = min((int)gy, 62);
            int iz = min((int)gz, 62);
            float fx = gx - (float)ix;
            float fy = gy - (float)iy;
            float fz = gz - (float)iz;
            const float* g = gbase + ((ix * GG + iy) * GG + iz);
            float v000 = g[0], v001 = g[1];
            float v010 = g[GG], v011 = g[GG + 1];
            float v100 = g[GG * GG], v101 = g[GG * GG + 1];
            float v110 = g[GG * GG + GG], v111 = g[GG * GG + GG + 1];
            float c00 = v000 + fz * (v001 - v000);
            float c01 = v010 + fz * (v011 - v010);
            float c10 = v100 + fz * (v101 - v100);
            float c11 = v110 + fz * (v111 - v110);
            float c0 = c00 + fy * (c01 - c00);
            float c1 = c10 + fy * (c11 - c10);
            v = (c0 + fx * (c1 - c0)) * sc;
        }
        float dk = v;
        dk = fminf(dk, __shfl_xor(dk, 1, 4));
        dk = fminf(dk, __shfl_xor(dk, 2, 4));
        float4 w0 = s_wT4[k * (OUTC / 4) + m * 2 + 0];
        float4 w1 = s_wT4[k * (OUTC / 4) + m * 2 + 1];
        acc[0] += dk * w0.x; acc[1] += dk * w0.y;
        acc[2] += dk * w0.z; acc[3] += dk * w0.w;
        acc[4] += dk * w1.x; acc[5] += dk * w1.y;
        acc[6] += dk * w1.z; acc[7] += dk * w1.w;
    }

    float* op = out + (size_t)(b * N + n) * OUTC + m * 8;
    *(float4*)&op[0] = make_float4(acc[0], acc[1], acc[2], acc[3]);
    *(float4*)&op[4] = make_float4(acc[4], acc[5], acc[6], acc[7]);
}

extern "C" void kernel_launch(void* const* d_in, const int* in_sizes, int n_in,
                              void* d_out, int out_size, void* d_ws, size_t ws_size,
                              hipStream_t stream) {
    const float* locs   = (const float*)d_in[0];
    const int*   idxs   = (const int*)d_in[1];
    const float* poses  = (const float*)d_in[2];
    const float* scales = (const float*)d_in[3];
    const float* sdf    = (const float*)d_in[4];
    const float* cells  = (const float*)d_in[5];
    const float* weight = (const float*)d_in[6];
    const float* bias   = (const float*)d_in[7];
    float* out = (float*)d_out;

    int B = in_sizes[1] / MM;          // idxs is [B, M]
    int N = in_sizes[0] / (3 * B);     // locs is [B, N, 3]
    int NSDF = in_sizes[4] / GG3;      // sdf_grid is [NSDF, G, G, G]
    int nslots = in_sizes[1];          // B*M

    size_t zp_bytes = (size_t)NSDF * GG3 * 4;
    dim3 grid((N + 63) / 64, B);

    if (ws_size >= zp_bytes) {
        unsigned int* zpg = (unsigned int*)d_ws;
        dim3 gridR(GG3 / 256, NSDF);
        repack_kernel<<<gridR, 256, 0, stream>>>(sdf, idxs, zpg, nslots);
        convsdf_zp_kernel<<<grid, 256, 0, stream>>>(locs, idxs, poses, scales,
                                                    zpg, cells, weight, bias,
                                                    out, N);
    } else {
        convsdf_direct_kernel<<<grid, 256, 0, stream>>>(locs, idxs, poses,
                                                        scales, sdf, cells,
                                                        weight, bias, out, N);
    }
}

// Round 8
// 28.215 us; speedup vs baseline: 1.7755x; 1.2243x over previous
//
#include <hip/hip_runtime.h>
#include <math.h>

#define KK 27
#define MM 4
#define OUTC 32
#define GG 64
#define GG3 (GG * GG * GG)
#define DILF 0.05f
#define MAXDF 1.0f
#define MU 4e-3f   // ambiguity margin in grid-units (u-space); FP drift bound ~1e-4

// Bit-exact (numpy op order, no FMA contraction, IEEE div) in-bounds test.
static __device__ inline bool exact_inb(float lx, float ly, float lz,
                                        float ox, float oy, float oz,
                                        float tx, float ty, float tz,
                                        float qx, float qy, float qz, float qw,
                                        float sc, float gcs) {
#pragma clang fp contract(off)
    float px = lx + ox, py = ly + oy, pz = lz + oz;
    float vx = px - tx, vy = py - ty, vz = pz - tz;
    float ux = -qx, uy = -qy, uz = -qz;
    float cx = uy * vz - uz * vy;
    float cy = uz * vx - ux * vz;
    float cz = ux * vy - uy * vx;
    float twx = cx + qw * vx;
    float twy = cy + qw * vy;
    float twz = cz + qw * vz;
    float rx = vx + 2.0f * (uy * twz - uz * twy);
    float ry = vy + 2.0f * (uz * twx - ux * twz);
    float rz = vz + 2.0f * (ux * twy - uy * twx);
    rx = rx / sc; ry = ry / sc; rz = rz / sc;
    return (rx >= 0.0f) & (rx <= gcs) & (ry >= 0.0f) & (ry <= gcs) &
           (rz >= 0.0f) & (rz <= gcs);
}

// Cross-lane min within each 4-lane quad via DPP quad_perm (VALU pipe,
// ~4 cyc, vs ~120 cyc ds_swizzle for __shfl_xor).
template <int CTRL>
static __device__ inline float dpp_qperm(float x) {
    int xi = __builtin_bit_cast(int, x);
    int r = __builtin_amdgcn_update_dpp(xi, xi, CTRL, 0xF, 0xF, false);
    return __builtin_bit_cast(float, r);
}

// Fused kernel; lane layout: 4 consecutive lanes = 4 models of one point.
__global__ __launch_bounds__(256) void convsdf_kernel(
    const float* __restrict__ locs, const int* __restrict__ idxs,
    const float* __restrict__ poses, const float* __restrict__ scales,
    const float* __restrict__ sdf, const float* __restrict__ cells,
    const float* __restrict__ weight, const float* __restrict__ bias,
    float* __restrict__ out, int N) {
    __shared__ float4 s_ro[MM][KK];
    __shared__ float4 s_off[KK];
    __shared__ float4 s_wT4[KK * OUTC / 4];
    __shared__ float  s_bias[OUTC];
    __shared__ float  s_t[MM][3];
    __shared__ float  s_q[MM][4];
    __shared__ float  s_sc[MM];
    __shared__ float  s_gcs[MM];
    __shared__ float  s_invscs[MM];
    __shared__ int    s_goff[MM];

    const int b = blockIdx.y;
    const int tid = threadIdx.x;

    float* s_wT = (float*)s_wT4;
    for (int i = tid; i < KK * OUTC; i += 256) {
        int k = i >> 5, o = i & 31;
        s_wT[i] = weight[o * KK + k];
    }
    if (tid < OUTC) s_bias[tid] = bias[tid];
    if (tid < KK) {
        int kx = tid / 9, ky = (tid / 3) % 3, kz = tid % 3;
        s_off[tid] = make_float4((float)(kx - 1) * DILF, (float)(ky - 1) * DILF,
                                 (float)(kz - 1) * DILF, 0.0f);
    }
    if (tid >= 128 && tid < 128 + MM) {
        int m = tid - 128;
        const float* pp = poses + (b * MM + m) * 7;
        float sc = scales[b * MM + m];
        int gi = idxs[b * MM + m];
        float cs = cells[gi];
        s_t[m][0] = pp[0]; s_t[m][1] = pp[1]; s_t[m][2] = pp[2];
        s_q[m][0] = pp[3]; s_q[m][1] = pp[4]; s_q[m][2] = pp[5]; s_q[m][3] = pp[6];
        s_sc[m] = sc;
        s_gcs[m] = (float)GG * cs;
        s_invscs[m] = 1.0f / (sc * cs);
        s_goff[m] = gi * GG3;
    }
    __syncthreads();

    if (tid < MM * KK) {
        int m = tid / KK, k = tid - m * KK;
        float4 off = s_off[k];
        float qx = s_q[m][0], qy = s_q[m][1], qz = s_q[m][2], qw = s_q[m][3];
        float ux = -qx, uy = -qy, uz = -qz;
        float vx = off.x, vy = off.y, vz = off.z;
        float cx = uy * vz - uz * vy + qw * vx;
        float cy = uz * vx - ux * vz + qw * vy;
        float cz = ux * vy - uy * vx + qw * vz;
        float rx = vx + 2.0f * (uy * cz - uz * cy);
        float ry = vy + 2.0f * (uz * cx - ux * cz);
        float rz = vz + 2.0f * (ux * cy - uy * cx);
        float f = s_invscs[m];
        s_ro[m][k] = make_float4(rx * f, ry * f, rz * f, 0.0f);
    }
    __syncthreads();

    const int pl = tid >> 2;          // point-in-block 0..63
    const int m  = tid & 3;           // model 0..3
    const int n  = blockIdx.x * 64 + pl;
    if (n >= N) return;

    const float* lp = locs + (size_t)(b * N + n) * 3;
    float lx = lp[0], ly = lp[1], lz = lp[2];

    float tx = s_t[m][0], ty = s_t[m][1], tz = s_t[m][2];
    float qx = s_q[m][0], qy = s_q[m][1], qz = s_q[m][2], qw = s_q[m][3];
    float sc = s_sc[m], gcs = s_gcs[m];
    float bux, buy, buz;
    {
        float vx = lx - tx, vy = ly - ty, vz = lz - tz;
        float ux = -qx, uy = -qy, uz = -qz;
        float cx = uy * vz - uz * vy + qw * vx;
        float cy = uz * vx - ux * vz + qw * vy;
        float cz = ux * vy - uy * vx + qw * vz;
        float rx = vx + 2.0f * (uy * cz - uz * cy);
        float ry = vy + 2.0f * (uz * cx - ux * cz);
        float rz = vz + 2.0f * (ux * cy - uy * cx);
        float f = s_invscs[m];
        bux = rx * f; buy = ry * f; buz = rz * f;
    }
    const float* gbase = sdf + s_goff[m];

    float acc[8];
#pragma unroll
    for (int j = 0; j < 8; ++j) acc[j] = s_bias[m * 8 + j];

#pragma unroll 3
    for (int k = 0; k < KK; ++k) {
        float4 ro = s_ro[m][k];
        float ux = bux + ro.x;
        float uy = buy + ro.y;
        float uz = buz + ro.z;
        float mn = fminf(fminf(ux, uy), uz);
        float mx = fmaxf(fmaxf(ux, uy), uz);
        bool inb = (mn >= 0.0f) & (mx <= 64.0f);
        // ambiguity via mn/mx algebra (rare; exact redo off the hot path)
        if ((mn > -MU) & (mx < 64.0f + MU) &
            ((mn < MU) | (mx > 64.0f - MU))) {
            float4 ofk = s_off[k];
            inb = exact_inb(lx, ly, lz, ofk.x, ofk.y, ofk.z,
                            tx, ty, tz, qx, qy, qz, qw, sc, gcs);
        }
        float v = MAXDF;
        if (inb) {   // exec-masked: OOB lanes issue no gathers
            float gx = fminf(fmaxf(ux - 0.5f, 0.0f), 63.0f);
            float gy = fminf(fmaxf(uy - 0.5f, 0.0f), 63.0f);
            float gz = fminf(fmaxf(uz - 0.5f, 0.0f), 63.0f);
            int ix = min((int)gx, 62);
            int iy = min((int)gy, 62);
            int iz = min((int)gz, 62);
            float fx = gx - (float)ix;
            float fy = gy - (float)iy;
            float fz = gz - (float)iz;
            const float* g = gbase + ((ix * GG + iy) * GG + iz);
            float v000 = g[0], v001 = g[1];
            float v010 = g[GG], v011 = g[GG + 1];
            float v100 = g[GG * GG], v101 = g[GG * GG + 1];
            float v110 = g[GG * GG + GG], v111 = g[GG * GG + GG + 1];
            float c00 = v000 + fz * (v001 - v000);
            float c01 = v010 + fz * (v011 - v010);
            float c10 = v100 + fz * (v101 - v100);
            float c11 = v110 + fz * (v111 - v110);
            float c0 = c00 + fy * (c01 - c00);
            float c1 = c10 + fy * (c11 - c10);
            v = (c0 + fx * (c1 - c0)) * sc;
        }
        // cross-model min within the 4-lane group via DPP quad_perm
        float dk = v;
        dk = fminf(dk, dpp_qperm<0xB1>(dk));   // [1,0,3,2] = xor 1
        dk = fminf(dk, dpp_qperm<0x4E>(dk));   // [2,3,0,1] = xor 2
        float4 w0 = s_wT4[k * (OUTC / 4) + m * 2 + 0];
        float4 w1 = s_wT4[k * (OUTC / 4) + m * 2 + 1];
        acc[0] += dk * w0.x; acc[1] += dk * w0.y;
        acc[2] += dk * w0.z; acc[3] += dk * w0.w;
        acc[4] += dk * w1.x; acc[5] += dk * w1.y;
        acc[6] += dk * w1.z; acc[7] += dk * w1.w;
    }

    float* op = out + (size_t)(b * N + n) * OUTC + m * 8;
    *(float4*)&op[0] = make_float4(acc[0], acc[1], acc[2], acc[3]);
    *(float4*)&op[4] = make_float4(acc[4], acc[5], acc[6], acc[7]);
}

extern "C" void kernel_launch(void* const* d_in, const int* in_sizes, int n_in,
                              void* d_out, int out_size, void* d_ws, size_t ws_size,
                              hipStream_t stream) {
    const float* locs   = (const float*)d_in[0];
    const int*   idxs   = (const int*)d_in[1];
    const float* poses  = (const float*)d_in[2];
    const float* scales = (const float*)d_in[3];
    const float* sdf    = (const float*)d_in[4];
    const float* cells  = (const float*)d_in[5];
    const float* weight = (const float*)d_in[6];
    const float* bias   = (const float*)d_in[7];
    float* out = (float*)d_out;

    int B = in_sizes[1] / MM;          // idxs is [B, M]
    int N = in_sizes[0] / (3 * B);     // locs is [B, N, 3]

    dim3 grid((N + 63) / 64, B);       // 64 points per 256-thread block
    convsdf_kernel<<<grid, 256, 0, stream>>>(locs, idxs, poses, scales, sdf,
                                             cells, weight, bias, out, N);
}